// Round 8
// baseline (487.645 us; speedup 1.0000x reference)
//
#include <hip/hip_runtime.h>

namespace {
constexpr int kB  = 16;
constexpr int kS  = 512;
constexpr int kH  = 768;
constexpr int kNH = 12;
constexpr int kHD = 64;
constexpr int kM  = kB * kS;   // 8192
}

typedef __attribute__((ext_vector_type(8))) short  short8;   // bf16x8 frag (4 VGPRs)
typedef __attribute__((ext_vector_type(4))) float  f32x4;    // MFMA acc / NT stores
typedef __attribute__((ext_vector_type(4))) unsigned short us4;
typedef __attribute__((ext_vector_type(2))) unsigned int   u32x2;

__device__ __forceinline__ unsigned short f2bf(float x) {
    unsigned u = __float_as_uint(x);
    return (unsigned short)((u + 0x7FFFu + ((u >> 16) & 1u)) >> 16);   // RNE
}

__device__ __forceinline__ unsigned pack_bf16(float lo, float hi) {
    return (unsigned)f2bf(lo) | ((unsigned)f2bf(hi) << 16);
}

__device__ __forceinline__ void load_lds16(const unsigned short* g, unsigned short* l) {
    __builtin_amdgcn_global_load_lds(
        (const __attribute__((address_space(1))) void*)g,
        (__attribute__((address_space(3))) void*)l,
        16, 0, 0);
}

// ---------------------------------------------------------------------------
// Fused fp32 -> bf16 conversion for hidden + Wq + Wk + Wv (one launch).
// ---------------------------------------------------------------------------
__global__ __launch_bounds__(256) void cvt_all_kernel(
    const float* __restrict__ hidden, const float* __restrict__ Wq,
    const float* __restrict__ Wk, const float* __restrict__ Wv,
    unsigned short* __restrict__ hbf, unsigned short* __restrict__ wqb,
    unsigned short* __restrict__ wkb, unsigned short* __restrict__ wvb)
{
    const int nH4 = (kM * kH) / 4;        // 1572864
    const int nW4 = (kH * kH) / 4;        // 147456
    int i = blockIdx.x * 256 + threadIdx.x;
    const float* src;
    unsigned short* dst;
    int off;
    if (i < nH4) {
        src = hidden; dst = hbf; off = i;
    } else {
        int j = i - nH4;
        int which = j / nW4;
        off = j - which * nW4;
        src = (which == 0) ? Wq : (which == 1) ? Wk : Wv;
        dst = (which == 0) ? wqb : (which == 1) ? wkb : wvb;
    }
    float4 v = reinterpret_cast<const float4*>(src)[off];
    us4 o;
    o.x = f2bf(v.x); o.y = f2bf(v.y); o.z = f2bf(v.z); o.w = f2bf(v.w);
    reinterpret_cast<us4*>(dst)[off] = o;
}

// ---------------------------------------------------------------------------
// QKV projection, bf16 MFMA, BK=64, swizzled LDS (unchanged from R7).
// Epilogue emits q,k hi/lo bf16 planes [b,h,s,d]; v bf16 transposed [b,h,d,s].
// ---------------------------------------------------------------------------
__global__ __launch_bounds__(256) void qkv_mfma_kernel(
    const unsigned short* __restrict__ hbf,
    const unsigned short* __restrict__ Wqb,
    const unsigned short* __restrict__ Wkb,
    const unsigned short* __restrict__ Wvb,
    const float* __restrict__ bq, const float* __restrict__ bk,
    const float* __restrict__ bv,
    unsigned short* __restrict__ qhi, unsigned short* __restrict__ qlo,
    unsigned short* __restrict__ khi, unsigned short* __restrict__ klo,
    unsigned short* __restrict__ vt)
{
    const int which = blockIdx.z;
    const unsigned short* W = (which == 0) ? Wqb : (which == 1) ? Wkb : Wvb;
    const float* bias       = (which == 0) ? bq  : (which == 1) ? bk  : bv;

    const int n0 = blockIdx.x * 128;
    const int m0 = blockIdx.y * 128;

    const int t    = threadIdx.x;
    const int lane = t & 63;
    const int w    = t >> 6;        // wave 0..3
    const int wm   = w >> 1;
    const int wn   = w & 1;

    __shared__ unsigned short As[128 * 64];   // [m][k64], swizzled
    __shared__ unsigned short Bs[128 * 64];   // [n][k64]

    f32x4 acc[4][4] = {};

    const int row8  = lane >> 3;              // 0..7
    const int sunit = (lane & 7) ^ row8;      // swizzled 16B unit
    const unsigned short* gA = hbf + (size_t)(m0 + w * 32 + row8) * kH + sunit * 8;
    const unsigned short* gB = W   + (size_t)(n0 + w * 32 + row8) * kH + sunit * 8;

    const int frow = lane & 15;
    const int fk   = (lane >> 4) * 8;         // 0,8,16,24
    const int fswz = (frow & 7) << 3;

    for (int k0 = 0; k0 < kH; k0 += 64) {
#pragma unroll
        for (int i = 0; i < 4; ++i) {
            load_lds16(gA + k0 + (size_t)(8 * i) * kH, &As[(w * 32 + 8 * i) * 64]);
            load_lds16(gB + k0 + (size_t)(8 * i) * kH, &Bs[(w * 32 + 8 * i) * 64]);
        }
        __syncthreads();

        short8 af[2][4], bf[2][4];
#pragma unroll
        for (int kk = 0; kk < 2; ++kk) {
#pragma unroll
            for (int i = 0; i < 4; ++i)
                af[kk][i] = *reinterpret_cast<const short8*>(
                    &As[(wm * 64 + i * 16 + frow) * 64 + ((kk * 32 + fk) ^ fswz)]);
#pragma unroll
            for (int j = 0; j < 4; ++j)
                bf[kk][j] = *reinterpret_cast<const short8*>(
                    &Bs[(wn * 64 + j * 16 + frow) * 64 + ((kk * 32 + fk) ^ fswz)]);
        }
#pragma unroll
        for (int kk = 0; kk < 2; ++kk)
#pragma unroll
            for (int i = 0; i < 4; ++i)
#pragma unroll
                for (int j = 0; j < 4; ++j)
                    acc[i][j] = __builtin_amdgcn_mfma_f32_16x16x32_bf16(
                        af[kk][i], bf[kk][j], acc[i][j], 0, 0, 0);
        __syncthreads();
    }

    const int col = lane & 15;
    const int rq4 = (lane >> 4) << 2;

    if (which < 2) {
        unsigned short* ohi = which ? khi : qhi;
        unsigned short* olo = which ? klo : qlo;
#pragma unroll
        for (int j = 0; j < 4; ++j) {
            const int n  = n0 + wn * 64 + j * 16 + col;
            const float bj = bias[n];
            const int hh = n >> 6, d = n & 63;
#pragma unroll
            for (int i = 0; i < 4; ++i) {
                const int mrow = m0 + wm * 64 + i * 16 + rq4;
                const int bb = mrow >> 9;
                const int ss = mrow & 511;
                const size_t base =
                    ((size_t)(bb * kNH + hh) * kS + ss) * kHD + d;
#pragma unroll
                for (int r = 0; r < 4; ++r) {
                    float x = acc[i][j][r] + bj;
                    unsigned short hi = f2bf(x);
                    float res = x - __uint_as_float((unsigned)hi << 16);
                    ohi[base + (size_t)r * kHD] = hi;
                    olo[base + (size_t)r * kHD] = f2bf(res);
                }
            }
        }
    } else {
#pragma unroll
        for (int j = 0; j < 4; ++j) {
            const int n  = n0 + wn * 64 + j * 16 + col;
            const float bj = bias[n];
            const int hh = n >> 6, d = n & 63;
#pragma unroll
            for (int i = 0; i < 4; ++i) {
                const int mrow = m0 + wm * 64 + i * 16 + rq4;
                const int bb = mrow >> 9;
                const int ss = mrow & 511;
                us4 o;
                o.x = f2bf(acc[i][j][0] + bj);
                o.y = f2bf(acc[i][j][1] + bj);
                o.z = f2bf(acc[i][j][2] + bj);
                o.w = f2bf(acc[i][j][3] + bj);
                *reinterpret_cast<us4*>(
                    &vt[((size_t)(bb * kNH + hh) * kHD + d) * kS + ss]) = o;
            }
        }
    }
}

// ---------------------------------------------------------------------------
// MFMA fused attention, LDS-FREE for K/V (this round's change).
// Swapped QK^T makes each lane's K-fragment (and V^T B-fragment) 16 B
// CONTIGUOUS in global memory -> load short8 directly global->VGPR.
// K/V are L2-resident (192 KB per bh, XCD-pinned by the swizzle); a block's
// 4 waves share tiles through L1 (24 KB/kt). Deletes all staging LDS, all
// __syncthreads, and the bank-conflicted LDS reads. Only the wave-private
// Pp bounce remains (same-wave lgkmcnt ordering; no barrier).
// Identical arithmetic/order -> bit-identical output vs R7.
// ---------------------------------------------------------------------------
__global__ __launch_bounds__(256, 2) void attn_kernel(
    const unsigned short* __restrict__ qhi, const unsigned short* __restrict__ qlo,
    const unsigned short* __restrict__ khi, const unsigned short* __restrict__ klo,
    const unsigned short* __restrict__ vtp, const float* __restrict__ mask,
    float* __restrict__ ctx, float* __restrict__ probs)
{
    const int bid = blockIdx.x;
    const int swz = (bid & 7) * 192 + (bid >> 3);   // 1536 = 8*192, bijective
    const int qt  = swz & 7;
    const int bh  = swz >> 3;
    const int b   = bh / kNH;
    const int h   = bh % kNH;
    const int q0  = qt * 64;

    const int t    = threadIdx.x;
    const int lane = t & 63;
    const int w    = t >> 6;        // wave 0..3
    const int g    = lane >> 4;     // 0..3
    const int fr   = lane & 15;

    __shared__ unsigned int Pp[4][576];   // per-wave packed P bounce (9 KB)

    // ---- Q fragments: direct global loads (one-time) ----
    const int qrow = q0 + w * 16 + fr;
    const unsigned short* qh = qhi + ((size_t)bh * kS + qrow) * kHD + g * 8;
    const unsigned short* ql = qlo + ((size_t)bh * kS + qrow) * kHD + g * 8;
    short8 qfh[2], qfl[2];
    qfh[0] = *reinterpret_cast<const short8*>(qh);
    qfh[1] = *reinterpret_cast<const short8*>(qh + 32);
    qfl[0] = *reinterpret_cast<const short8*>(ql);
    qfl[1] = *reinterpret_cast<const short8*>(ql + 32);

    // ---- per-lane fragment base pointers (contiguous 16B units) ----
    // K planes [bh][s][d]: lane needs row (kt*64+ks*16+fr), elems d2*32+g*8..+7
    const unsigned short* kh_p = khi + (size_t)bh * kS * kHD + fr * kHD + g * 8;
    const unsigned short* kl_p = klo + (size_t)bh * kS * kHD + fr * kHD + g * 8;
    // V^T [bh][d][s]: lane needs row (dt*16+fr), elems kt*64+kp*32+g*8..+7
    const unsigned short* vt_p = vtp + (size_t)bh * kHD * kS + fr * kS + g * 8;

    unsigned pk[8][4][2];           // packed bf16 P, whole 512-k row (64 VGPR)
    f32x4 cacc[4] = {};             // ctx acc: 4 d-tiles
    float rs = 0.0f;
    const float* mrow = mask + b * kS;

#pragma unroll
    for (int kt = 0; kt < 8; ++kt) {
        // V fragments: issue early, consumed after QK^T (ILP hides L2 latency)
        short8 vb[2][4];
#pragma unroll
        for (int kp = 0; kp < 2; ++kp)
#pragma unroll
            for (int dt = 0; dt < 4; ++dt)
                vb[kp][dt] = *reinterpret_cast<const short8*>(
                    vt_p + (size_t)dt * (16 * kS) + kt * 64 + kp * 32);

        // ---- QK^T (swapped): S^T[k][q], hi/lo split, exp + pack ----
#pragma unroll
        for (int ks = 0; ks < 4; ++ks) {
            f32x4 sa = {};
#pragma unroll
            for (int d2 = 0; d2 < 2; ++d2) {
                const size_t koff = (size_t)(kt * 64 + ks * 16) * kHD + d2 * 32;
                short8 ah = *reinterpret_cast<const short8*>(kh_p + koff);
                short8 al = *reinterpret_cast<const short8*>(kl_p + koff);
                sa = __builtin_amdgcn_mfma_f32_16x16x32_bf16(ah, qfh[d2], sa, 0, 0, 0);
                sa = __builtin_amdgcn_mfma_f32_16x16x32_bf16(ah, qfl[d2], sa, 0, 0, 0);
                sa = __builtin_amdgcn_mfma_f32_16x16x32_bf16(al, qfh[d2], sa, 0, 0, 0);
            }
            const float4 mv = *reinterpret_cast<const float4*>(
                &mrow[kt * 64 + ks * 16 + g * 4]);
            float p0 = __expf(fmaf(sa[0], 0.125f, fmaf(mv.x, 1e4f, -1e4f)));
            float p1 = __expf(fmaf(sa[1], 0.125f, fmaf(mv.y, 1e4f, -1e4f)));
            float p2 = __expf(fmaf(sa[2], 0.125f, fmaf(mv.z, 1e4f, -1e4f)));
            float p3 = __expf(fmaf(sa[3], 0.125f, fmaf(mv.w, 1e4f, -1e4f)));
            rs += (p0 + p1) + (p2 + p3);
            const unsigned u0 = pack_bf16(p0, p1);
            const unsigned u1 = pack_bf16(p2, p3);
            pk[kt][ks][0] = u0;
            pk[kt][ks][1] = u1;
            *reinterpret_cast<u32x2*>(&Pp[w][fr * 36 + ks * 8 + g * 2]) =
                (u32x2){u0, u1};
        }

        // ---- PV: ctx[q][d] += P[q][k] * V[k][d]  (wave-private Pp bounce) ----
#pragma unroll
        for (int kp = 0; kp < 2; ++kp) {
            short8 pa = *reinterpret_cast<const short8*>(
                &Pp[w][fr * 36 + kp * 16 + g * 4]);
#pragma unroll
            for (int dt = 0; dt < 4; ++dt)
                cacc[dt] = __builtin_amdgcn_mfma_f32_16x16x32_bf16(
                    pa, vb[kp][dt], cacc[dt], 0, 0, 0);
        }
    }

    // ---- row sums (q = fr is lane-local; reduce over g groups) ----
    rs += __shfl_xor(rs, 16, 64);
    rs += __shfl_xor(rs, 32, 64);
    const float inv = 1.0f / rs;

    // ---- single normalized probs write (streaming) ----
    float* prow = probs + ((size_t)bh * kS + qrow) * kS;
#pragma unroll
    for (int kt = 0; kt < 8; ++kt)
#pragma unroll
        for (int ks = 0; ks < 4; ++ks) {
            const unsigned u0 = pk[kt][ks][0], u1 = pk[kt][ks][1];
            f32x4 o;
            o.x = __uint_as_float(u0 << 16) * inv;
            o.y = __uint_as_float(u0 & 0xFFFF0000u) * inv;
            o.z = __uint_as_float(u1 << 16) * inv;
            o.w = __uint_as_float(u1 & 0xFFFF0000u) * inv;
            __builtin_nontemporal_store(
                o, reinterpret_cast<f32x4*>(prow + kt * 64 + ks * 16 + g * 4));
        }

    // ---- ctx write: rows q = g*4+r need inv from lane (g*4+r) ----
    float invr[4];
#pragma unroll
    for (int r = 0; r < 4; ++r) invr[r] = __shfl(inv, g * 4 + r, 64);
    float* crow = ctx + ((size_t)(b * kS + q0 + w * 16 + g * 4)) * kH
                      + h * kHD + fr;
#pragma unroll
    for (int dt = 0; dt < 4; ++dt)
#pragma unroll
        for (int r = 0; r < 4; ++r)
            __builtin_nontemporal_store(cacc[dt][r] * invr[r],
                                        crow + (size_t)r * kH + dt * 16);
}

extern "C" void kernel_launch(void* const* d_in, const int* in_sizes, int n_in,
                              void* d_out, int out_size, void* d_ws, size_t ws_size,
                              hipStream_t stream) {
    (void)in_sizes; (void)n_in; (void)out_size; (void)ws_size;

    const float* hidden = (const float*)d_in[0];
    const float* mask   = (const float*)d_in[1];
    const float* Wq     = (const float*)d_in[2];
    const float* bq     = (const float*)d_in[3];
    const float* Wk     = (const float*)d_in[4];
    const float* bk     = (const float*)d_in[5];
    const float* Wv     = (const float*)d_in[6];
    const float* bv     = (const float*)d_in[7];

    float* ctx   = (float*)d_out;
    float* probs = (float*)d_out + (size_t)kB * kS * kH;

    // ws layout: bf16 hidden + bf16 weights, then bf16 q(hi,lo)/k(hi,lo)/vT.
    unsigned short* hbf = (unsigned short*)d_ws;
    unsigned short* wqb = hbf + (size_t)kM * kH;
    unsigned short* wkb = wqb + (size_t)kH * kH;
    unsigned short* wvb = wkb + (size_t)kH * kH;
    unsigned short* qhi = wvb + (size_t)kH * kH;
    const size_t nqkv = (size_t)kB * kNH * kS * kHD;   // 6291456
    unsigned short* qlo = qhi + nqkv;
    unsigned short* khi = qlo + nqkv;
    unsigned short* klo = khi + nqkv;
    unsigned short* vt  = klo + nqkv;

    const int ncvt = ((kM * kH) / 4 + 3 * (kH * kH) / 4) / 256;
    cvt_all_kernel<<<ncvt, 256, 0, stream>>>(hidden, Wq, Wk, Wv,
                                             hbf, wqb, wkb, wvb);

    dim3 gp(kH / 128, kM / 128, 3);       // (6, 64, 3)
    qkv_mfma_kernel<<<gp, 256, 0, stream>>>(hbf, wqb, wkb, wvb,
                                            bq, bk, bv,
                                            qhi, qlo, khi, klo, vt);

    attn_kernel<<<dim3(kB * kNH * (kS / 64)), 256, 0, stream>>>(
        qhi, qlo, khi, klo, vt, mask, ctx, probs);
}

// Round 9
// 383.493 us; speedup vs baseline: 1.2716x; 1.2716x over previous
//
#include <hip/hip_runtime.h>

namespace {
constexpr int kB  = 16;
constexpr int kS  = 512;
constexpr int kH  = 768;
constexpr int kNH = 12;
constexpr int kHD = 64;
constexpr int kM  = kB * kS;   // 8192
}

typedef __attribute__((ext_vector_type(8))) short  short8;   // bf16x8 frag (4 VGPRs)
typedef __attribute__((ext_vector_type(4))) float  f32x4;    // MFMA acc / NT stores
typedef __attribute__((ext_vector_type(4))) unsigned short us4;
typedef __attribute__((ext_vector_type(2))) unsigned int   u32x2;

__device__ __forceinline__ unsigned short f2bf(float x) {
    unsigned u = __float_as_uint(x);
    return (unsigned short)((u + 0x7FFFu + ((u >> 16) & 1u)) >> 16);   // RNE
}

__device__ __forceinline__ unsigned pack_bf16(float lo, float hi) {
    return (unsigned)f2bf(lo) | ((unsigned)f2bf(hi) << 16);
}

__device__ __forceinline__ void load_lds16(const unsigned short* g, unsigned short* l) {
    __builtin_amdgcn_global_load_lds(
        (const __attribute__((address_space(1))) void*)g,
        (__attribute__((address_space(3))) void*)l,
        16, 0, 0);
}

// ---------------------------------------------------------------------------
// Fused fp32 -> bf16 conversion for hidden + Wq + Wk + Wv (one launch).
// ---------------------------------------------------------------------------
__global__ __launch_bounds__(256) void cvt_all_kernel(
    const float* __restrict__ hidden, const float* __restrict__ Wq,
    const float* __restrict__ Wk, const float* __restrict__ Wv,
    unsigned short* __restrict__ hbf, unsigned short* __restrict__ wqb,
    unsigned short* __restrict__ wkb, unsigned short* __restrict__ wvb)
{
    const int nH4 = (kM * kH) / 4;        // 1572864
    const int nW4 = (kH * kH) / 4;        // 147456
    int i = blockIdx.x * 256 + threadIdx.x;
    const float* src;
    unsigned short* dst;
    int off;
    if (i < nH4) {
        src = hidden; dst = hbf; off = i;
    } else {
        int j = i - nH4;
        int which = j / nW4;
        off = j - which * nW4;
        src = (which == 0) ? Wq : (which == 1) ? Wk : Wv;
        dst = (which == 0) ? wqb : (which == 1) ? wkb : wvb;
    }
    float4 v = reinterpret_cast<const float4*>(src)[off];
    us4 o;
    o.x = f2bf(v.x); o.y = f2bf(v.y); o.z = f2bf(v.z); o.w = f2bf(v.w);
    reinterpret_cast<us4*>(dst)[off] = o;
}

// ---------------------------------------------------------------------------
// QKV projection, bf16 MFMA, BK=64, swizzled LDS.
// NEW this round: for q/k blocks the MFMA operand order is SWAPPED
// (mfma(W,h) -> D^T): reg now indexes n (=d), lane indexes m, so each
// thread's 4 acc values are consecutive in d -> hi/lo epilogue stores are
// 8-byte us4 (32/thread) instead of 128 scattered 2-byte stores.
// Same per-dot arithmetic & order -> bit-identical output.
// v blocks keep the original orientation ([b,h,d,s] wants consecutive s).
// ---------------------------------------------------------------------------
__global__ __launch_bounds__(256) void qkv_mfma_kernel(
    const unsigned short* __restrict__ hbf,
    const unsigned short* __restrict__ Wqb,
    const unsigned short* __restrict__ Wkb,
    const unsigned short* __restrict__ Wvb,
    const float* __restrict__ bq, const float* __restrict__ bk,
    const float* __restrict__ bv,
    unsigned short* __restrict__ qhi, unsigned short* __restrict__ qlo,
    unsigned short* __restrict__ khi, unsigned short* __restrict__ klo,
    unsigned short* __restrict__ vt)
{
    const int which = blockIdx.z;
    const unsigned short* W = (which == 0) ? Wqb : (which == 1) ? Wkb : Wvb;
    const float* bias       = (which == 0) ? bq  : (which == 1) ? bk  : bv;

    const int n0 = blockIdx.x * 128;
    const int m0 = blockIdx.y * 128;

    const int t    = threadIdx.x;
    const int lane = t & 63;
    const int w    = t >> 6;        // wave 0..3
    const int wm   = w >> 1;
    const int wn   = w & 1;

    __shared__ unsigned short As[128 * 64];   // [m][k64], swizzled
    __shared__ unsigned short Bs[128 * 64];   // [n][k64]

    f32x4 acc[4][4] = {};

    const int row8  = lane >> 3;              // 0..7
    const int sunit = (lane & 7) ^ row8;      // swizzled 16B unit
    const unsigned short* gA = hbf + (size_t)(m0 + w * 32 + row8) * kH + sunit * 8;
    const unsigned short* gB = W   + (size_t)(n0 + w * 32 + row8) * kH + sunit * 8;

    const int frow = lane & 15;
    const int fk   = (lane >> 4) * 8;         // 0,8,16,24
    const int fswz = (frow & 7) << 3;

    for (int k0 = 0; k0 < kH; k0 += 64) {
#pragma unroll
        for (int i = 0; i < 4; ++i) {
            load_lds16(gA + k0 + (size_t)(8 * i) * kH, &As[(w * 32 + 8 * i) * 64]);
            load_lds16(gB + k0 + (size_t)(8 * i) * kH, &Bs[(w * 32 + 8 * i) * 64]);
        }
        __syncthreads();

        short8 af[2][4], bf[2][4];
#pragma unroll
        for (int kk = 0; kk < 2; ++kk) {
#pragma unroll
            for (int i = 0; i < 4; ++i)
                af[kk][i] = *reinterpret_cast<const short8*>(
                    &As[(wm * 64 + i * 16 + frow) * 64 + ((kk * 32 + fk) ^ fswz)]);
#pragma unroll
            for (int j = 0; j < 4; ++j)
                bf[kk][j] = *reinterpret_cast<const short8*>(
                    &Bs[(wn * 64 + j * 16 + frow) * 64 + ((kk * 32 + fk) ^ fswz)]);
        }
        if (which < 2) {
            // swapped: acc[i][j], i = n-tile (A=W), j = m-tile (B=h)
#pragma unroll
            for (int kk = 0; kk < 2; ++kk)
#pragma unroll
                for (int i = 0; i < 4; ++i)
#pragma unroll
                    for (int j = 0; j < 4; ++j)
                        acc[i][j] = __builtin_amdgcn_mfma_f32_16x16x32_bf16(
                            bf[kk][i], af[kk][j], acc[i][j], 0, 0, 0);
        } else {
            // original: acc[i][j], i = m-tile (A=h), j = n-tile (B=W)
#pragma unroll
            for (int kk = 0; kk < 2; ++kk)
#pragma unroll
                for (int i = 0; i < 4; ++i)
#pragma unroll
                    for (int j = 0; j < 4; ++j)
                        acc[i][j] = __builtin_amdgcn_mfma_f32_16x16x32_bf16(
                            af[kk][i], bf[kk][j], acc[i][j], 0, 0, 0);
        }
        __syncthreads();
    }

    const int col = lane & 15;
    const int rq4 = (lane >> 4) << 2;

    if (which < 2) {
        unsigned short* ohi = which ? khi : qhi;
        unsigned short* olo = which ? klo : qlo;
#pragma unroll
        for (int i = 0; i < 4; ++i) {
            const int nb = n0 + wn * 64 + i * 16 + rq4;   // 4 consecutive d
            const float4 b4 = *reinterpret_cast<const float4*>(&bias[nb]);
            const int hh = nb >> 6, d0 = nb & 63;
#pragma unroll
            for (int j = 0; j < 4; ++j) {
                const int m  = m0 + wm * 64 + j * 16 + col;
                const int bb = m >> 9;
                const int ss = m & 511;
                const size_t base =
                    ((size_t)(bb * kNH + hh) * kS + ss) * kHD + d0;
                float x0 = acc[i][j][0] + b4.x;
                float x1 = acc[i][j][1] + b4.y;
                float x2 = acc[i][j][2] + b4.z;
                float x3 = acc[i][j][3] + b4.w;
                us4 oh, ol;
                oh.x = f2bf(x0); oh.y = f2bf(x1); oh.z = f2bf(x2); oh.w = f2bf(x3);
                ol.x = f2bf(x0 - __uint_as_float((unsigned)oh.x << 16));
                ol.y = f2bf(x1 - __uint_as_float((unsigned)oh.y << 16));
                ol.z = f2bf(x2 - __uint_as_float((unsigned)oh.z << 16));
                ol.w = f2bf(x3 - __uint_as_float((unsigned)oh.w << 16));
                *reinterpret_cast<us4*>(ohi + base) = oh;
                *reinterpret_cast<us4*>(olo + base) = ol;
            }
        }
    } else {
#pragma unroll
        for (int j = 0; j < 4; ++j) {
            const int n  = n0 + wn * 64 + j * 16 + col;
            const float bj = bias[n];
            const int hh = n >> 6, d = n & 63;
#pragma unroll
            for (int i = 0; i < 4; ++i) {
                const int mrow = m0 + wm * 64 + i * 16 + rq4;
                const int bb = mrow >> 9;
                const int ss = mrow & 511;
                us4 o;
                o.x = f2bf(acc[i][j][0] + bj);
                o.y = f2bf(acc[i][j][1] + bj);
                o.z = f2bf(acc[i][j][2] + bj);
                o.w = f2bf(acc[i][j][3] + bj);
                *reinterpret_cast<us4*>(
                    &vt[((size_t)(bb * kNH + hh) * kHD + d) * kS + ss]) = o;
            }
        }
    }
}

// ---------------------------------------------------------------------------
// MFMA fused attention — REVERTED to the R7 LDS double-buffered version
// (R8's LDS-free variant was latency-bound: 202 µs, MfmaUtil 5%).
// Double-buffered K/V tiles, 1 barrier/kt, setprio around compute;
// swapped QK^T with hi/lo split; bf16 PV with V^T; probs written once.
// ---------------------------------------------------------------------------
__global__ __launch_bounds__(256) void attn_kernel(
    const unsigned short* __restrict__ qhi, const unsigned short* __restrict__ qlo,
    const unsigned short* __restrict__ khi, const unsigned short* __restrict__ klo,
    const unsigned short* __restrict__ vtp, const float* __restrict__ mask,
    float* __restrict__ ctx, float* __restrict__ probs)
{
    const int bid = blockIdx.x;
    const int swz = (bid & 7) * 192 + (bid >> 3);   // 1536 = 8*192, bijective
    const int qt  = swz & 7;
    const int bh  = swz >> 3;
    const int b   = bh / kNH;
    const int h   = bh % kNH;
    const int q0  = qt * 64;

    const int t    = threadIdx.x;
    const int lane = t & 63;
    const int w    = t >> 6;        // wave 0..3
    const int g    = lane >> 4;     // 0..3
    const int fr   = lane & 15;

    __shared__ unsigned short Khs[2][4096];   // 64k x 64d bf16, src-swizzled
    __shared__ unsigned short Kls[2][4096];
    __shared__ unsigned short Vts[2][4096];   // 64d x 64s bf16, src-swizzled
    __shared__ unsigned int   Pp[4][576];     // per-wave packed P (wave-private)

    // ---- Q fragments: direct global loads (one-time) ----
    const int qrow = q0 + w * 16 + fr;
    const unsigned short* qh = qhi + ((size_t)bh * kS + qrow) * kHD + g * 8;
    const unsigned short* ql = qlo + ((size_t)bh * kS + qrow) * kHD + g * 8;
    const short8 qfh0 = *reinterpret_cast<const short8*>(qh);
    const short8 qfh1 = *reinterpret_cast<const short8*>(qh + 32);
    const short8 qfl0 = *reinterpret_cast<const short8*>(ql);
    const short8 qfl1 = *reinterpret_cast<const short8*>(ql + 32);

    // ---- staging: chunk c = (w*2+i)*64 + lane; src pre-swizzled ----
    const int c0 = (w * 2 + 0) * 64 + lane;
    const int c1 = (w * 2 + 1) * 64 + lane;
    const int r0 = c0 >> 3, r1 = c1 >> 3;
    const int s0b = ((c0 & 7) * 16) ^ ((r0 & 7) << 4);
    const int s1b = ((c1 & 7) * 16) ^ ((r1 & 7) << 4);
    const int ko0 = r0 * 128 + s0b,  ko1 = r1 * 128 + s1b;     // K tile: 128B rows
    const int vo0 = r0 * 1024 + s0b, vo1 = r1 * 1024 + s1b;    // VT: 1024B glob rows
    const char* kh_b = (const char*)(khi + (size_t)bh * kS * kHD);
    const char* kl_b = (const char*)(klo + (size_t)bh * kS * kHD);
    const char* vt_b = (const char*)(vtp + (size_t)bh * kHD * kS);
    const int l0 = (w * 2 + 0) * 512;
    const int l1 = (w * 2 + 1) * 512;

    unsigned pk[8][4][2];           // packed bf16 P, whole 512-k row (64 VGPR)
    f32x4 cacc[4] = {};             // ctx acc: 4 d-tiles
    float rs = 0.0f;
    const float* mrow = mask + b * kS;

    // ---- prologue: stage tile 0 into buffer 0 ----
    load_lds16((const unsigned short*)(kh_b + ko0), &Khs[0][l0]);
    load_lds16((const unsigned short*)(kh_b + ko1), &Khs[0][l1]);
    load_lds16((const unsigned short*)(kl_b + ko0), &Kls[0][l0]);
    load_lds16((const unsigned short*)(kl_b + ko1), &Kls[0][l1]);
    load_lds16((const unsigned short*)(vt_b + vo0), &Vts[0][l0]);
    load_lds16((const unsigned short*)(vt_b + vo1), &Vts[0][l1]);

#pragma unroll
    for (int kt = 0; kt < 8; ++kt) {
        const int cur = kt & 1;
        __syncthreads();            // drains vmcnt(0): buf[cur] staged; all
                                    // waves done reading buf[cur^1]

        if (kt < 7) {               // issue next-tile loads; fly under compute
            const int nxt = cur ^ 1;
            load_lds16((const unsigned short*)(kh_b + (kt + 1) * 8192 + ko0), &Khs[nxt][l0]);
            load_lds16((const unsigned short*)(kh_b + (kt + 1) * 8192 + ko1), &Khs[nxt][l1]);
            load_lds16((const unsigned short*)(kl_b + (kt + 1) * 8192 + ko0), &Kls[nxt][l0]);
            load_lds16((const unsigned short*)(kl_b + (kt + 1) * 8192 + ko1), &Kls[nxt][l1]);
            load_lds16((const unsigned short*)(vt_b + (kt + 1) * 128 + vo0), &Vts[nxt][l0]);
            load_lds16((const unsigned short*)(vt_b + (kt + 1) * 128 + vo1), &Vts[nxt][l1]);
        }

        __builtin_amdgcn_s_setprio(1);

        // ---- QK^T (swapped): S^T[k][q], hi/lo split, then exp+pack ----
#pragma unroll
        for (int ks = 0; ks < 4; ++ks) {
            f32x4 sa = {};
#pragma unroll
            for (int d2 = 0; d2 < 2; ++d2) {
                const int kr  = ks * 16 + fr;
                const int off = kr * 128 + ((d2 * 64 + g * 16) ^ ((kr & 7) << 4));
                short8 ah = *reinterpret_cast<const short8*>((const char*)Khs[cur] + off);
                short8 al = *reinterpret_cast<const short8*>((const char*)Kls[cur] + off);
                const short8 qhf = d2 ? qfh1 : qfh0;
                const short8 qlf = d2 ? qfl1 : qfl0;
                sa = __builtin_amdgcn_mfma_f32_16x16x32_bf16(ah, qhf, sa, 0, 0, 0);
                sa = __builtin_amdgcn_mfma_f32_16x16x32_bf16(ah, qlf, sa, 0, 0, 0);
                sa = __builtin_amdgcn_mfma_f32_16x16x32_bf16(al, qhf, sa, 0, 0, 0);
            }
            const float4 mv = *reinterpret_cast<const float4*>(
                &mrow[kt * 64 + ks * 16 + g * 4]);
            float p0 = __expf(fmaf(sa[0], 0.125f, fmaf(mv.x, 1e4f, -1e4f)));
            float p1 = __expf(fmaf(sa[1], 0.125f, fmaf(mv.y, 1e4f, -1e4f)));
            float p2 = __expf(fmaf(sa[2], 0.125f, fmaf(mv.z, 1e4f, -1e4f)));
            float p3 = __expf(fmaf(sa[3], 0.125f, fmaf(mv.w, 1e4f, -1e4f)));
            rs += (p0 + p1) + (p2 + p3);
            const unsigned u0 = pack_bf16(p0, p1);
            const unsigned u1 = pack_bf16(p2, p3);
            pk[kt][ks][0] = u0;
            pk[kt][ks][1] = u1;
            *reinterpret_cast<u32x2*>(&Pp[w][fr * 36 + ks * 8 + g * 2]) =
                (u32x2){u0, u1};
        }

        // ---- PV: ctx[q][d] += P[q][k] * V[k][d]  (wave-private Pp bounce) ----
#pragma unroll
        for (int kp = 0; kp < 2; ++kp) {
            short8 pa = *reinterpret_cast<const short8*>(
                &Pp[w][fr * 36 + kp * 16 + g * 4]);
#pragma unroll
            for (int dt = 0; dt < 4; ++dt) {
                const int vr  = dt * 16 + fr;
                const int off = vr * 128 + ((kp * 64 + g * 16) ^ ((vr & 7) << 4));
                short8 vb = *reinterpret_cast<const short8*>((const char*)Vts[cur] + off);
                cacc[dt] = __builtin_amdgcn_mfma_f32_16x16x32_bf16(
                    pa, vb, cacc[dt], 0, 0, 0);
            }
        }

        __builtin_amdgcn_s_setprio(0);
    }

    // ---- row sums (q = fr is lane-local; reduce over g groups) ----
    rs += __shfl_xor(rs, 16, 64);
    rs += __shfl_xor(rs, 32, 64);
    const float inv = 1.0f / rs;

    // ---- single normalized probs write (streaming) ----
    float* prow = probs + ((size_t)bh * kS + qrow) * kS;
#pragma unroll
    for (int kt = 0; kt < 8; ++kt)
#pragma unroll
        for (int ks = 0; ks < 4; ++ks) {
            const unsigned u0 = pk[kt][ks][0], u1 = pk[kt][ks][1];
            f32x4 o;
            o.x = __uint_as_float(u0 << 16) * inv;
            o.y = __uint_as_float(u0 & 0xFFFF0000u) * inv;
            o.z = __uint_as_float(u1 << 16) * inv;
            o.w = __uint_as_float(u1 & 0xFFFF0000u) * inv;
            __builtin_nontemporal_store(
                o, reinterpret_cast<f32x4*>(prow + kt * 64 + ks * 16 + g * 4));
        }

    // ---- ctx write: rows q = g*4+r need inv from lane (g*4+r) ----
    float invr[4];
#pragma unroll
    for (int r = 0; r < 4; ++r) invr[r] = __shfl(inv, g * 4 + r, 64);
    float* crow = ctx + ((size_t)(b * kS + q0 + w * 16 + g * 4)) * kH
                      + h * kHD + fr;
#pragma unroll
    for (int dt = 0; dt < 4; ++dt)
#pragma unroll
        for (int r = 0; r < 4; ++r)
            __builtin_nontemporal_store(cacc[dt][r] * invr[r],
                                        crow + (size_t)r * kH + dt * 16);
}

extern "C" void kernel_launch(void* const* d_in, const int* in_sizes, int n_in,
                              void* d_out, int out_size, void* d_ws, size_t ws_size,
                              hipStream_t stream) {
    (void)in_sizes; (void)n_in; (void)out_size; (void)ws_size;

    const float* hidden = (const float*)d_in[0];
    const float* mask   = (const float*)d_in[1];
    const float* Wq     = (const float*)d_in[2];
    const float* bq     = (const float*)d_in[3];
    const float* Wk     = (const float*)d_in[4];
    const float* bk     = (const float*)d_in[5];
    const float* Wv     = (const float*)d_in[6];
    const float* bv     = (const float*)d_in[7];

    float* ctx   = (float*)d_out;
    float* probs = (float*)d_out + (size_t)kB * kS * kH;

    // ws layout: bf16 hidden + bf16 weights, then bf16 q(hi,lo)/k(hi,lo)/vT.
    unsigned short* hbf = (unsigned short*)d_ws;
    unsigned short* wqb = hbf + (size_t)kM * kH;
    unsigned short* wkb = wqb + (size_t)kH * kH;
    unsigned short* wvb = wkb + (size_t)kH * kH;
    unsigned short* qhi = wvb + (size_t)kH * kH;
    const size_t nqkv = (size_t)kB * kNH * kS * kHD;   // 6291456
    unsigned short* qlo = qhi + nqkv;
    unsigned short* khi = qlo + nqkv;
    unsigned short* klo = khi + nqkv;
    unsigned short* vt  = klo + nqkv;

    const int ncvt = ((kM * kH) / 4 + 3 * (kH * kH) / 4) / 256;
    cvt_all_kernel<<<ncvt, 256, 0, stream>>>(hidden, Wq, Wk, Wv,
                                             hbf, wqb, wkb, wvb);

    dim3 gp(kH / 128, kM / 128, 3);       // (6, 64, 3)
    qkv_mfma_kernel<<<gp, 256, 0, stream>>>(hbf, wqb, wkb, wvb,
                                            bq, bk, bv,
                                            qhi, qlo, khi, klo, vt);

    attn_kernel<<<dim3(kB * kNH * (kS / 64)), 256, 0, stream>>>(
        qhi, qlo, khi, klo, vt, mask, ctx, probs);
}

// Round 10
// 375.013 us; speedup vs baseline: 1.3003x; 1.0226x over previous
//
#include <hip/hip_runtime.h>

namespace {
constexpr int kB  = 16;
constexpr int kS  = 512;
constexpr int kH  = 768;
constexpr int kNH = 12;
constexpr int kHD = 64;
constexpr int kM  = kB * kS;   // 8192
}

typedef __attribute__((ext_vector_type(8))) short  short8;   // bf16x8 frag (4 VGPRs)
typedef __attribute__((ext_vector_type(4))) float  f32x4;    // MFMA acc / NT stores
typedef __attribute__((ext_vector_type(4))) unsigned short us4;
typedef __attribute__((ext_vector_type(2))) unsigned int   u32x2;

__device__ __forceinline__ unsigned short f2bf(float x) {
    unsigned u = __float_as_uint(x);
    return (unsigned short)((u + 0x7FFFu + ((u >> 16) & 1u)) >> 16);   // RNE
}

__device__ __forceinline__ unsigned pack_bf16(float lo, float hi) {
    return (unsigned)f2bf(lo) | ((unsigned)f2bf(hi) << 16);
}

__device__ __forceinline__ void load_lds16(const unsigned short* g, unsigned short* l) {
    __builtin_amdgcn_global_load_lds(
        (const __attribute__((address_space(1))) void*)g,
        (__attribute__((address_space(3))) void*)l,
        16, 0, 0);
}

// ---------------------------------------------------------------------------
// Fused fp32 -> bf16 conversion for hidden + Wq + Wk + Wv (one launch).
// ---------------------------------------------------------------------------
__global__ __launch_bounds__(256) void cvt_all_kernel(
    const float* __restrict__ hidden, const float* __restrict__ Wq,
    const float* __restrict__ Wk, const float* __restrict__ Wv,
    unsigned short* __restrict__ hbf, unsigned short* __restrict__ wqb,
    unsigned short* __restrict__ wkb, unsigned short* __restrict__ wvb)
{
    const int nH4 = (kM * kH) / 4;        // 1572864
    const int nW4 = (kH * kH) / 4;        // 147456
    int i = blockIdx.x * 256 + threadIdx.x;
    const float* src;
    unsigned short* dst;
    int off;
    if (i < nH4) {
        src = hidden; dst = hbf; off = i;
    } else {
        int j = i - nH4;
        int which = j / nW4;
        off = j - which * nW4;
        src = (which == 0) ? Wq : (which == 1) ? Wk : Wv;
        dst = (which == 0) ? wqb : (which == 1) ? wkb : wvb;
    }
    float4 v = reinterpret_cast<const float4*>(src)[off];
    us4 o;
    o.x = f2bf(v.x); o.y = f2bf(v.y); o.z = f2bf(v.z); o.w = f2bf(v.w);
    reinterpret_cast<us4*>(dst)[off] = o;
}

// ---------------------------------------------------------------------------
// QKV projection, bf16 MFMA, BK=64, swizzled LDS (unchanged from R9).
// q/k blocks use swapped MFMA operands (reg indexes d) -> us4 hi/lo stores.
// v blocks original orientation -> [b,h,d,s] transposed us4 stores.
// ---------------------------------------------------------------------------
__global__ __launch_bounds__(256) void qkv_mfma_kernel(
    const unsigned short* __restrict__ hbf,
    const unsigned short* __restrict__ Wqb,
    const unsigned short* __restrict__ Wkb,
    const unsigned short* __restrict__ Wvb,
    const float* __restrict__ bq, const float* __restrict__ bk,
    const float* __restrict__ bv,
    unsigned short* __restrict__ qhi, unsigned short* __restrict__ qlo,
    unsigned short* __restrict__ khi, unsigned short* __restrict__ klo,
    unsigned short* __restrict__ vt)
{
    const int which = blockIdx.z;
    const unsigned short* W = (which == 0) ? Wqb : (which == 1) ? Wkb : Wvb;
    const float* bias       = (which == 0) ? bq  : (which == 1) ? bk  : bv;

    const int n0 = blockIdx.x * 128;
    const int m0 = blockIdx.y * 128;

    const int t    = threadIdx.x;
    const int lane = t & 63;
    const int w    = t >> 6;        // wave 0..3
    const int wm   = w >> 1;
    const int wn   = w & 1;

    __shared__ unsigned short As[128 * 64];   // [m][k64], swizzled
    __shared__ unsigned short Bs[128 * 64];   // [n][k64]

    f32x4 acc[4][4] = {};

    const int row8  = lane >> 3;              // 0..7
    const int sunit = (lane & 7) ^ row8;      // swizzled 16B unit
    const unsigned short* gA = hbf + (size_t)(m0 + w * 32 + row8) * kH + sunit * 8;
    const unsigned short* gB = W   + (size_t)(n0 + w * 32 + row8) * kH + sunit * 8;

    const int frow = lane & 15;
    const int fk   = (lane >> 4) * 8;         // 0,8,16,24
    const int fswz = (frow & 7) << 3;

    for (int k0 = 0; k0 < kH; k0 += 64) {
#pragma unroll
        for (int i = 0; i < 4; ++i) {
            load_lds16(gA + k0 + (size_t)(8 * i) * kH, &As[(w * 32 + 8 * i) * 64]);
            load_lds16(gB + k0 + (size_t)(8 * i) * kH, &Bs[(w * 32 + 8 * i) * 64]);
        }
        __syncthreads();

        short8 af[2][4], bf[2][4];
#pragma unroll
        for (int kk = 0; kk < 2; ++kk) {
#pragma unroll
            for (int i = 0; i < 4; ++i)
                af[kk][i] = *reinterpret_cast<const short8*>(
                    &As[(wm * 64 + i * 16 + frow) * 64 + ((kk * 32 + fk) ^ fswz)]);
#pragma unroll
            for (int j = 0; j < 4; ++j)
                bf[kk][j] = *reinterpret_cast<const short8*>(
                    &Bs[(wn * 64 + j * 16 + frow) * 64 + ((kk * 32 + fk) ^ fswz)]);
        }
        if (which < 2) {
#pragma unroll
            for (int kk = 0; kk < 2; ++kk)
#pragma unroll
                for (int i = 0; i < 4; ++i)
#pragma unroll
                    for (int j = 0; j < 4; ++j)
                        acc[i][j] = __builtin_amdgcn_mfma_f32_16x16x32_bf16(
                            bf[kk][i], af[kk][j], acc[i][j], 0, 0, 0);
        } else {
#pragma unroll
            for (int kk = 0; kk < 2; ++kk)
#pragma unroll
                for (int i = 0; i < 4; ++i)
#pragma unroll
                    for (int j = 0; j < 4; ++j)
                        acc[i][j] = __builtin_amdgcn_mfma_f32_16x16x32_bf16(
                            af[kk][i], bf[kk][j], acc[i][j], 0, 0, 0);
        }
        __syncthreads();
    }

    const int col = lane & 15;
    const int rq4 = (lane >> 4) << 2;

    if (which < 2) {
        unsigned short* ohi = which ? khi : qhi;
        unsigned short* olo = which ? klo : qlo;
#pragma unroll
        for (int i = 0; i < 4; ++i) {
            const int nb = n0 + wn * 64 + i * 16 + rq4;   // 4 consecutive d
            const float4 b4 = *reinterpret_cast<const float4*>(&bias[nb]);
            const int hh = nb >> 6, d0 = nb & 63;
#pragma unroll
            for (int j = 0; j < 4; ++j) {
                const int m  = m0 + wm * 64 + j * 16 + col;
                const int bb = m >> 9;
                const int ss = m & 511;
                const size_t base =
                    ((size_t)(bb * kNH + hh) * kS + ss) * kHD + d0;
                float x0 = acc[i][j][0] + b4.x;
                float x1 = acc[i][j][1] + b4.y;
                float x2 = acc[i][j][2] + b4.z;
                float x3 = acc[i][j][3] + b4.w;
                us4 oh, ol;
                oh.x = f2bf(x0); oh.y = f2bf(x1); oh.z = f2bf(x2); oh.w = f2bf(x3);
                ol.x = f2bf(x0 - __uint_as_float((unsigned)oh.x << 16));
                ol.y = f2bf(x1 - __uint_as_float((unsigned)oh.y << 16));
                ol.z = f2bf(x2 - __uint_as_float((unsigned)oh.z << 16));
                ol.w = f2bf(x3 - __uint_as_float((unsigned)oh.w << 16));
                *reinterpret_cast<us4*>(ohi + base) = oh;
                *reinterpret_cast<us4*>(olo + base) = ol;
            }
        }
    } else {
#pragma unroll
        for (int j = 0; j < 4; ++j) {
            const int n  = n0 + wn * 64 + j * 16 + col;
            const float bj = bias[n];
            const int hh = n >> 6, d = n & 63;
#pragma unroll
            for (int i = 0; i < 4; ++i) {
                const int mrow = m0 + wm * 64 + i * 16 + rq4;
                const int bb = mrow >> 9;
                const int ss = mrow & 511;
                us4 o;
                o.x = f2bf(acc[i][j][0] + bj);
                o.y = f2bf(acc[i][j][1] + bj);
                o.z = f2bf(acc[i][j][2] + bj);
                o.w = f2bf(acc[i][j][3] + bj);
                *reinterpret_cast<us4*>(
                    &vt[((size_t)(bb * kNH + hh) * kHD + d) * kS + ss]) = o;
            }
        }
    }
}

// ---------------------------------------------------------------------------
// MFMA fused attention — QBLK=128 this round: 8 waves x 16 q-rows per block.
// Same verified per-wave structure as R6/R9 (dbuf K/V, 1 barrier/kt, setprio,
// swapped QK^T hi/lo, bf16 PV with V^T, probs once). Scaling effects:
//   - K/V staging amortized over 2x q-rows (total gload_lds traffic halves;
//     3 staging insts/wave/kt instead of 6)
//   - occupancy 8 -> 16 waves/CU (LDS 66.6 KB, 2 blocks/CU) = 2x TLP
// Per-q-row arithmetic identical -> bit-identical output.
// ---------------------------------------------------------------------------
__global__ __launch_bounds__(512) void attn_kernel(
    const unsigned short* __restrict__ qhi, const unsigned short* __restrict__ qlo,
    const unsigned short* __restrict__ khi, const unsigned short* __restrict__ klo,
    const unsigned short* __restrict__ vtp, const float* __restrict__ mask,
    float* __restrict__ ctx, float* __restrict__ probs)
{
    const int bid = blockIdx.x;
    const int swz = (bid & 7) * 96 + (bid >> 3);   // 768 = 8*96, bijective
    const int qt  = swz & 3;
    const int bh  = swz >> 2;
    const int b   = bh / kNH;
    const int h   = bh % kNH;
    const int q0  = qt * 128;

    const int t    = threadIdx.x;
    const int lane = t & 63;
    const int w    = t >> 6;        // wave 0..7
    const int g    = lane >> 4;     // 0..3
    const int fr   = lane & 15;

    __shared__ unsigned short Khs[2][4096];   // 64k x 64d bf16, src-swizzled
    __shared__ unsigned short Kls[2][4096];
    __shared__ unsigned short Vts[2][4096];   // 64d x 64s bf16, src-swizzled
    __shared__ unsigned int   Pp[8][576];     // per-wave packed P (wave-private)

    // ---- Q fragments: direct global loads (one-time) ----
    const int qrow = q0 + w * 16 + fr;
    const unsigned short* qh = qhi + ((size_t)bh * kS + qrow) * kHD + g * 8;
    const unsigned short* ql = qlo + ((size_t)bh * kS + qrow) * kHD + g * 8;
    const short8 qfh0 = *reinterpret_cast<const short8*>(qh);
    const short8 qfh1 = *reinterpret_cast<const short8*>(qh + 32);
    const short8 qfl0 = *reinterpret_cast<const short8*>(ql);
    const short8 qfl1 = *reinterpret_cast<const short8*>(ql + 32);

    // ---- staging: 8 waves, 1 chunk (1 KB) per wave per tile ----
    const int c  = w * 64 + lane;             // 0..511 covers 8 KB tile
    const int r  = c >> 3;                    // tile row 0..63
    const int sb = ((c & 7) * 16) ^ ((r & 7) << 4);
    const int ko = r * 128 + sb;              // K tile: 128 B global rows
    const int vo = r * 1024 + sb;             // VT: 1024 B global rows
    const char* kh_b = (const char*)(khi + (size_t)bh * kS * kHD);
    const char* kl_b = (const char*)(klo + (size_t)bh * kS * kHD);
    const char* vt_b = (const char*)(vtp + (size_t)bh * kHD * kS);
    const int l = w * 512;                    // LDS chunk (wave-uniform)

    unsigned pk[8][4][2];           // packed bf16 P, whole 512-k row (64 VGPR)
    f32x4 cacc[4] = {};             // ctx acc: 4 d-tiles
    float rs = 0.0f;
    const float* mrow = mask + b * kS;

    // ---- prologue: stage tile 0 into buffer 0 ----
    load_lds16((const unsigned short*)(kh_b + ko), &Khs[0][l]);
    load_lds16((const unsigned short*)(kl_b + ko), &Kls[0][l]);
    load_lds16((const unsigned short*)(vt_b + vo), &Vts[0][l]);

#pragma unroll
    for (int kt = 0; kt < 8; ++kt) {
        const int cur = kt & 1;
        __syncthreads();            // drains vmcnt(0): buf[cur] staged; all
                                    // waves done reading buf[cur^1]

        if (kt < 7) {               // issue next-tile loads; fly under compute
            const int nxt = cur ^ 1;
            load_lds16((const unsigned short*)(kh_b + (kt + 1) * 8192 + ko), &Khs[nxt][l]);
            load_lds16((const unsigned short*)(kl_b + (kt + 1) * 8192 + ko), &Kls[nxt][l]);
            load_lds16((const unsigned short*)(vt_b + (kt + 1) * 128 + vo), &Vts[nxt][l]);
        }

        __builtin_amdgcn_s_setprio(1);

        // ---- QK^T (swapped): S^T[k][q], hi/lo split, then exp+pack ----
#pragma unroll
        for (int ks = 0; ks < 4; ++ks) {
            f32x4 sa = {};
#pragma unroll
            for (int d2 = 0; d2 < 2; ++d2) {
                const int kr  = ks * 16 + fr;
                const int off = kr * 128 + ((d2 * 64 + g * 16) ^ ((kr & 7) << 4));
                short8 ah = *reinterpret_cast<const short8*>((const char*)Khs[cur] + off);
                short8 al = *reinterpret_cast<const short8*>((const char*)Kls[cur] + off);
                const short8 qhf = d2 ? qfh1 : qfh0;
                const short8 qlf = d2 ? qfl1 : qfl0;
                sa = __builtin_amdgcn_mfma_f32_16x16x32_bf16(ah, qhf, sa, 0, 0, 0);
                sa = __builtin_amdgcn_mfma_f32_16x16x32_bf16(ah, qlf, sa, 0, 0, 0);
                sa = __builtin_amdgcn_mfma_f32_16x16x32_bf16(al, qhf, sa, 0, 0, 0);
            }
            const float4 mv = *reinterpret_cast<const float4*>(
                &mrow[kt * 64 + ks * 16 + g * 4]);
            float p0 = __expf(fmaf(sa[0], 0.125f, fmaf(mv.x, 1e4f, -1e4f)));
            float p1 = __expf(fmaf(sa[1], 0.125f, fmaf(mv.y, 1e4f, -1e4f)));
            float p2 = __expf(fmaf(sa[2], 0.125f, fmaf(mv.z, 1e4f, -1e4f)));
            float p3 = __expf(fmaf(sa[3], 0.125f, fmaf(mv.w, 1e4f, -1e4f)));
            rs += (p0 + p1) + (p2 + p3);
            const unsigned u0 = pack_bf16(p0, p1);
            const unsigned u1 = pack_bf16(p2, p3);
            pk[kt][ks][0] = u0;
            pk[kt][ks][1] = u1;
            *reinterpret_cast<u32x2*>(&Pp[w][fr * 36 + ks * 8 + g * 2]) =
                (u32x2){u0, u1};
        }

        // ---- PV: ctx[q][d] += P[q][k] * V[k][d]  (wave-private Pp bounce) ----
#pragma unroll
        for (int kp = 0; kp < 2; ++kp) {
            short8 pa = *reinterpret_cast<const short8*>(
                &Pp[w][fr * 36 + kp * 16 + g * 4]);
#pragma unroll
            for (int dt = 0; dt < 4; ++dt) {
                const int vr  = dt * 16 + fr;
                const int off = vr * 128 + ((kp * 64 + g * 16) ^ ((vr & 7) << 4));
                short8 vb = *reinterpret_cast<const short8*>((const char*)Vts[cur] + off);
                cacc[dt] = __builtin_amdgcn_mfma_f32_16x16x32_bf16(
                    pa, vb, cacc[dt], 0, 0, 0);
            }
        }

        __builtin_amdgcn_s_setprio(0);
    }

    // ---- row sums (q = fr is lane-local; reduce over g groups) ----
    rs += __shfl_xor(rs, 16, 64);
    rs += __shfl_xor(rs, 32, 64);
    const float inv = 1.0f / rs;

    // ---- single normalized probs write (streaming) ----
    float* prow = probs + ((size_t)bh * kS + qrow) * kS;
#pragma unroll
    for (int kt = 0; kt < 8; ++kt)
#pragma unroll
        for (int ks = 0; ks < 4; ++ks) {
            const unsigned u0 = pk[kt][ks][0], u1 = pk[kt][ks][1];
            f32x4 o;
            o.x = __uint_as_float(u0 << 16) * inv;
            o.y = __uint_as_float(u0 & 0xFFFF0000u) * inv;
            o.z = __uint_as_float(u1 << 16) * inv;
            o.w = __uint_as_float(u1 & 0xFFFF0000u) * inv;
            __builtin_nontemporal_store(
                o, reinterpret_cast<f32x4*>(prow + kt * 64 + ks * 16 + g * 4));
        }

    // ---- ctx write: rows q = g*4+r need inv from lane (g*4+r) ----
    float invr[4];
#pragma unroll
    for (int r4 = 0; r4 < 4; ++r4) invr[r4] = __shfl(inv, g * 4 + r4, 64);
    float* crow = ctx + ((size_t)(b * kS + q0 + w * 16 + g * 4)) * kH
                      + h * kHD + fr;
#pragma unroll
    for (int dt = 0; dt < 4; ++dt)
#pragma unroll
        for (int r4 = 0; r4 < 4; ++r4)
            __builtin_nontemporal_store(cacc[dt][r4] * invr[r4],
                                        crow + (size_t)r4 * kH + dt * 16);
}

extern "C" void kernel_launch(void* const* d_in, const int* in_sizes, int n_in,
                              void* d_out, int out_size, void* d_ws, size_t ws_size,
                              hipStream_t stream) {
    (void)in_sizes; (void)n_in; (void)out_size; (void)ws_size;

    const float* hidden = (const float*)d_in[0];
    const float* mask   = (const float*)d_in[1];
    const float* Wq     = (const float*)d_in[2];
    const float* bq     = (const float*)d_in[3];
    const float* Wk     = (const float*)d_in[4];
    const float* bk     = (const float*)d_in[5];
    const float* Wv     = (const float*)d_in[6];
    const float* bv     = (const float*)d_in[7];

    float* ctx   = (float*)d_out;
    float* probs = (float*)d_out + (size_t)kB * kS * kH;

    // ws layout: bf16 hidden + bf16 weights, then bf16 q(hi,lo)/k(hi,lo)/vT.
    unsigned short* hbf = (unsigned short*)d_ws;
    unsigned short* wqb = hbf + (size_t)kM * kH;
    unsigned short* wkb = wqb + (size_t)kH * kH;
    unsigned short* wvb = wkb + (size_t)kH * kH;
    unsigned short* qhi = wvb + (size_t)kH * kH;
    const size_t nqkv = (size_t)kB * kNH * kS * kHD;   // 6291456
    unsigned short* qlo = qhi + nqkv;
    unsigned short* khi = qlo + nqkv;
    unsigned short* klo = khi + nqkv;
    unsigned short* vt  = klo + nqkv;

    const int ncvt = ((kM * kH) / 4 + 3 * (kH * kH) / 4) / 256;
    cvt_all_kernel<<<ncvt, 256, 0, stream>>>(hidden, Wq, Wk, Wv,
                                             hbf, wqb, wkb, wvb);

    dim3 gp(kH / 128, kM / 128, 3);       // (6, 64, 3)
    qkv_mfma_kernel<<<gp, 256, 0, stream>>>(hbf, wqb, wkb, wvb,
                                            bq, bk, bv,
                                            qhi, qlo, khi, klo, vt);

    attn_kernel<<<dim3(kB * kNH * (kS / 128)), 512, 0, stream>>>(
        qhi, qlo, khi, klo, vt, mask, ctx, probs);
}